// Round 3
// baseline (40.042 us; speedup 1.0000x reference)
//
#include <hip/hip_runtime.h>

// RandomFilter: per-image 3x3 depthwise correlation, impulse at [2,2].
// img: [32, 3, 512, 512] fp32; noise: [32, 3, 3] fp32.
// out[b,c,h,w] = clip( sum img_pad[h+kh-1][w+kw-1] * (0.1*noise[b] + delta22)[kh][kw], 0, 1 )
//
// R3 structure: thread = 4-row x 8-col tile. Per input row: 4 dense float4 loads
// ([w0-4],[w0],[w0+4],[w0+8]) -> zero strided sub-word loads (R2 had 12 strided
// scalars per 16 outputs; those were the TA hogs). Wave = one full 512-wide row
// segment (lane == 8-col group), so only lanes 0/63 predicate halo loads.

#define RF_H 512
#define RF_W 512
#define RF_C 3
#define RF_SIGMA 0.1f

__global__ __launch_bounds__(256, 4) void RandomFilter_40767829574170_kernel(
    const float* __restrict__ img,
    const float* __restrict__ noise,
    float* __restrict__ out)
{
    const int idx   = blockIdx.x * 256 + threadIdx.x;
    const int wg    = idx & 63;            // 8-col group == lane
    const int strip = (idx >> 6) & 127;    // 4-row strip
    const int plane = idx >> 13;           // 0..95 (b*3 + c), uniform per block
    const int b     = plane / RF_C;

    // 3x3 weight from noise (9 uniform loads, L1 broadcast).
    const float* np_ = noise + b * 9;
    float wgt[3][3];
    #pragma unroll
    for (int r = 0; r < 3; ++r)
        #pragma unroll
        for (int s = 0; s < 3; ++s)
            wgt[r][s] = RF_SIGMA * np_[r * 3 + s];
    wgt[2][2] += 1.0f;  // impulse at [2,2] (center = ceil(K/2))

    const float* P  = img + plane * (RF_H * RF_W);
    const int    w0 = wg * 8;
    const int    h0 = strip * 4;

    float acc[4][8];
    #pragma unroll
    for (int o = 0; o < 4; ++o)
        #pragma unroll
        for (int j = 0; j < 8; ++j) acc[o][j] = 0.0f;

    #pragma unroll
    for (int r = 0; r < 6; ++r) {
        const int hr = h0 - 1 + r;
        if (hr >= 0 && hr < RF_H) {        // wave-uniform branch (strip uniform)
            const float* row = P + (hr << 9);
            const float4 z4 = make_float4(0.f, 0.f, 0.f, 0.f);
            // v[0..15] = in[w0-4 .. w0+11]; windows use v[3..12].
            const float4 A = (wg > 0)  ? *reinterpret_cast<const float4*>(row + w0 - 4) : z4;
            const float4 B =             *reinterpret_cast<const float4*>(row + w0);
            const float4 C =             *reinterpret_cast<const float4*>(row + w0 + 4);
            const float4 D = (wg < 63) ? *reinterpret_cast<const float4*>(row + w0 + 8) : z4;
            float v[16];
            v[0]=A.x;  v[1]=A.y;  v[2]=A.z;  v[3]=A.w;
            v[4]=B.x;  v[5]=B.y;  v[6]=B.z;  v[7]=B.w;
            v[8]=C.x;  v[9]=C.y;  v[10]=C.z; v[11]=C.w;
            v[12]=D.x; v[13]=D.y; v[14]=D.z; v[15]=D.w;
            #pragma unroll
            for (int o = 0; o < 4; ++o) {
                const int kr = r - o;              // compile-time after unroll
                if (kr >= 0 && kr <= 2) {
                    const float k0 = wgt[kr][0], k1 = wgt[kr][1], k2 = wgt[kr][2];
                    #pragma unroll
                    for (int j = 0; j < 8; ++j)
                        acc[o][j] += k0 * v[3 + j] + k1 * v[4 + j] + k2 * v[5 + j];
                }
            }
        }
    }

    float* outP = out + plane * (RF_H * RF_W) + w0;
    #pragma unroll
    for (int o = 0; o < 4; ++o) {
        float t[8];
        #pragma unroll
        for (int j = 0; j < 8; ++j) {
            float y = acc[o][j];
            y = isnan(y) ? 1.0f : y;           // reference nan -> 1.0
            t[j] = fminf(fmaxf(y, 0.0f), 1.0f); // clip (v_med3)
        }
        float4 lo, hi;
        lo.x=t[0]; lo.y=t[1]; lo.z=t[2]; lo.w=t[3];
        hi.x=t[4]; hi.y=t[5]; hi.z=t[6]; hi.w=t[7];
        float* orow = outP + ((h0 + o) << 9);
        *reinterpret_cast<float4*>(orow)     = lo;
        *reinterpret_cast<float4*>(orow + 4) = hi;
    }
}

extern "C" void kernel_launch(void* const* d_in, const int* in_sizes, int n_in,
                              void* d_out, int out_size, void* d_ws, size_t ws_size,
                              hipStream_t stream) {
    const float* img   = (const float*)d_in[0];
    const float* noise = (const float*)d_in[1];
    float* out = (float*)d_out;

    // 96 planes * 128 strips * 64 col-groups = 786,432 threads = 3072 blocks
    const int grid = 96 * 128 * 64 / 256;
    RandomFilter_40767829574170_kernel<<<grid, 256, 0, stream>>>(img, noise, out);
}